// Round 2
// 188.870 us; speedup vs baseline: 1.2532x; 1.2532x over previous
//
#include <hip/hip_runtime.h>

// InputPreprocessor — B=2048, N=32, M=8, D_PAIR=37, H=128.
// features_el_el in the reference is DEAD CODE. Live outputs (both f32):
//   out0 = features_el  [B,N,424]  (ion-summed 2-layer silu MLP || flat feats)
//   out1 = features_ion [B,8,32]
// R9 = R8 + bugfix. R8's NaN: featbL slots 6,7 (k=38,39 pad lanes of the
// bias-feature chunk) were never initialized; on iteration 0 they hold raw
// LDS garbage, and bf16 Inf/NaN patterns there give 0.0*Inf = NaN inside the
// layer-0 MFMA. Fix: prologue zero/one-init of slots 5,6,7 (as R7 had).
// For it>=1 those slots are clobbered by h0 leftovers — finite silu outputs —
// and multiply a guaranteed-0.0 W0L row, contributing exactly 0.
//
// R8 structure kept: h0 layer0->layer1 handoff via LDS round-trip (bf16
// [16 edges][128 ch] per wave, row-XOR swizzle short_off ^= (edge&7)<<3;
// conflict-free b64 writes / b128 reads) replacing 64x ds_bpermute + selects.
// h0 ALIASES featL/featbL (dead after bf0/bf1 reg load; wave-private,
// in-order LDS pipe => no barriers). LDS total 81920 B = exactly 2 blocks/CU.
// bf16 packing via v_cvt_pk_bf16_f32. 1/(d+eps) via rcpf. b1 hoisted.
// __launch_bounds__(512,4) pins VGPR<=128 so 4 waves/SIMD residency holds.

typedef __attribute__((ext_vector_type(8))) short short8;
typedef __attribute__((ext_vector_type(4))) float f32x4;

#define ITERS     8
#define UNITS_IT  16          // units per block-iteration (128 edges)
#define ROWLEN    424
#define OUT_EL    27787264    // 65536*424

__device__ __forceinline__ unsigned short f2bf(float f){   // prologue staging only
    unsigned int u = __builtin_bit_cast(unsigned int, f);
    u += 0x7fffu + ((u >> 16) & 1u);     // RNE
    return (unsigned short)(u >> 16);
}
__device__ __forceinline__ unsigned int cvtpk_bf16(float lo, float hi){
    unsigned int r;
    asm("v_cvt_pk_bf16_f32 %0, %1, %2" : "=v"(r) : "v"(lo), "v"(hi));
    return r;   // [15:0]=bf16(lo), [31:16]=bf16(hi), RNE
}
__device__ __forceinline__ unsigned short bf16s(float x){
    return (unsigned short)cvtpk_bf16(x, x);
}
__device__ __forceinline__ float fast_silu(float x){
    return x * __builtin_amdgcn_rcpf(1.0f + __expf(-x));
}

__global__ __launch_bounds__(512, 4)
void el_kernel(const float* __restrict__ r,
               const float* __restrict__ Rion,
               const float* __restrict__ W0,
               const float* __restrict__ b0,
               const float* __restrict__ W1,
               const float* __restrict__ b1,
               float* __restrict__ out)
{
    // MFMA-read layouts are [tile][chunk][lane64][8 shorts]: b128 = base+lane*16.
    __shared__ __align__(16) unsigned short W0L[8][2][64][8];   // 16384 B
    __shared__ __align__(16) unsigned short W1L[8][4][64][8];   // 32768 B
    // Per-wave 4096B union:
    //   shorts [0,512)    : featL  [4][16][8]  (feat^T k=0..31)      — feature phase
    //   shorts [512,640)  : featbL [16][8]     (k=32..36, 37=1.0)    — feature phase
    //   shorts [0,2048)   : h0     [16 edges][128 ch], XOR-swizzled  — layer0->layer1
    __shared__ __align__(16) unsigned short UNI[8][2048];       // 32768 B
    // total 81920 B -> exactly 2 blocks (1024 thr) / CU

    const int t    = threadIdx.x;
    const int lane = t & 63;
    const int w    = t >> 6;       // wave 0..7, owns units 2w,2w+1 (16 edges)
    const int quad = lane >> 4;
    const int l16  = lane & 15;

    // ---- stage W0L: A-frag for layer 0 (M=channel, K=feature) ----
    for (int i = t; i < 8*2*64*8; i += 512){
        int j = i & 7, ln = (i >> 3) & 63, ch = (i >> 9) & 1, tc = i >> 10;
        int q = ln >> 4, n = tc*16 + (ln & 15);
        float v = 0.f;
        if (ch == 0)            v = W0[(q*8 + j)*128 + n];
        else if (q == 0){
            if      (j < 5)     v = W0[(32 + j)*128 + n];
            else if (j == 5)    v = b0[n];                 // bias via 1.0-feature
        }
        ((unsigned short*)W0L)[i] = f2bf(v);
    }
    // ---- stage W1L: B-frag for layer 1 (K=channel, N=out-channel) ----
    for (int i = t; i < 8*4*64*8; i += 512){
        int j = i & 7, ln = (i >> 3) & 63, c = (i >> 9) & 3, tc = i >> 11;
        int k = c*32 + (ln >> 4)*8 + j, n = tc*16 + (ln & 15);
        ((unsigned short*)W1L)[i] = f2bf(W1[k*128 + n]);
    }
    // ---- featbL constant slots (iteration 0): j=5 -> 1.0, j=6,7 -> 0.
    // Without this, it=0 reads raw LDS garbage there; a bf16 Inf/NaN pattern
    // times the 0.0 weight row poisons the MFMA (0*Inf=NaN). For it>=1 these
    // slots hold finite h0 leftovers (x 0.0 weight = exact 0), and j=5 is
    // rewritten each iteration in the feature phase.
    if (t < 128){
        UNI[t >> 4][512 + (t & 15)*8 + 5] = 0x3F80;
        UNI[t >> 4][512 + (t & 15)*8 + 6] = 0;
        UNI[t >> 4][512 + (t & 15)*8 + 7] = 0;
    }

    // feature-phase mapping: 4 threads per edge; wave-local (frow>>4 == w)
    const int frow  = t >> 2;      // edge 0..127 = ul*8 + m
    const int phase = t & 3;
    const int ul    = frow >> 3;   // block-local unit 0..15
    const int m     = frow & 7;
    const int e16   = frow & 15;   // wave-local edge
    const float Rx = Rion[m*3+0];
    const float Ry = Rion[m*3+1];
    const float Rz = Rion[m*3+2];

    unsigned short* const uw = &UNI[w][0];
    const int h0row = l16 * 128;            // short offset of this lane's h0 row
    const int swz   = (l16 & 7) << 3;       // row-XOR swizzle (short granularity)

    const f32x4 zeroc = {0.f,0.f,0.f,0.f};

    // hoist layer-1 bias (8 VGPRs)
    float bias1[8];
    #pragma unroll
    for (int tc = 0; tc < 8; ++tc) bias1[tc] = b1[tc*16 + l16];

    __syncthreads();   // weights staged; loop body is wave-local (no in-loop barriers)

    const int ubase0 = blockIdx.x * (UNITS_IT * ITERS);

    for (int it = 0; it < ITERS; ++it){
        const int ubase = ubase0 + it * UNITS_IT;

        // ---------- features: bf16 -> featL/featbL + exact f32 -> out ----------
        {
            int gu = ubase + ul;
            float dx = r[gu*3+0] - Rx;
            float dy = r[gu*3+1] - Ry;
            float dz = r[gu*3+2] - Rz;
            float d2 = dx*dx + dy*dy + dz*dz;
            float d  = __builtin_amdgcn_sqrtf(d2);
            float* orow = &out[(size_t)gu*ROWLEN + 128 + m*37];
            for (int f = phase; f < 37; f += 4){
                float val;
                if (f < 32){
                    float q  = (float)f * (1.0f/31.0f);
                    float mu = q*q*5.0f;
                    float is = 7.0f * __builtin_amdgcn_rcpf(1.0f + 5.0f*q);
                    float uu = (d - mu) * is;
                    val = d2 * __expf(-d - uu*uu);
                } else if (f == 32) val = d;
                else if (f == 33)   val = __builtin_amdgcn_rcpf(d + 0.01f);
                else if (f == 34)   val = dx;
                else if (f == 35)   val = dy;
                else                val = dz;
                orow[f] = val;
                unsigned short ub = bf16s(val);
                if (f < 32) uw[(f >> 3)*128 + e16*8 + (f & 7)] = ub;
                else        uw[512 + e16*8 + (f - 32)]          = ub;
            }
            // h0 of previous iteration clobbered the union: rewrite the
            // 1.0 bias-feature slot every iteration.
            if (phase == 3) uw[512 + e16*8 + 5] = 0x3F80;
        }

        // ---------- layer 0 (transposed): D0 = W0^T @ feat^T ----------
        short8 bf0 = *(const short8*)&uw[quad*128 + l16*8];   // k = quad*8+j
        short8 bf1 = *(const short8*)&uw[512 + l16*8];        // k = 32+j
        // featL/featbL now dead in LDS -> h0 may overwrite the union.
        #pragma unroll
        for (int tc = 0; tc < 8; ++tc){
            short8 a0 = *(const short8*)&W0L[tc][0][lane][0];
            short8 a1 = *(const short8*)&W0L[tc][1][lane][0];
            f32x4 acc = __builtin_amdgcn_mfma_f32_16x16x32_bf16(a0, bf0, zeroc, 0, 0, 0);
            acc       = __builtin_amdgcn_mfma_f32_16x16x32_bf16(a1, bf1, acc,   0, 0, 0);
            // C-layout: lane holds ch n = tc*16 + quad*4 + rr, edge = l16.
            unsigned int p01 = cvtpk_bf16(fast_silu(acc[0]), fast_silu(acc[1]));
            unsigned int p23 = cvtpk_bf16(fast_silu(acc[2]), fast_silu(acc[3]));
            unsigned long long pk = (unsigned long long)p01 |
                                    ((unsigned long long)p23 << 32);
            // h0[edge=l16][ch], swizzled; b64 write, conflict-free
            *(unsigned long long*)&uw[h0row + ((tc*16 + quad*4) ^ swz)] = pk;
        }

        // ---------- layer 1: D1[e][n] = h0[e][k] W1[k][n] ----------
        // A-frag: lane needs h0[edge=l16][k=c*32+quad*8+j]; same row-XOR swizzle.
        short8 afk[4];
        #pragma unroll
        for (int c = 0; c < 4; ++c)
            afk[c] = *(const short8*)&uw[h0row + ((c*32 + quad*8) ^ swz)];

        f32x4 acc1[8];
        #pragma unroll
        for (int i = 0; i < 8; ++i) acc1[i] = zeroc;
        #pragma unroll
        for (int c = 0; c < 4; ++c){
            #pragma unroll
            for (int tc = 0; tc < 8; ++tc){
                short8 bw = *(const short8*)&W1L[tc][c][lane][0];
                acc1[tc] = __builtin_amdgcn_mfma_f32_16x16x32_bf16(afk[c], bw, acc1[tc], 0, 0, 0);
            }
        }
        // bias + silu + ion-sum over rows, store one_el f32
        #pragma unroll
        for (int tc = 0; tc < 8; ++tc){
            float v = 0.f;
            #pragma unroll
            for (int rr = 0; rr < 4; ++rr) v += fast_silu(acc1[tc][rr] + bias1[tc]);
            v += __shfl_xor(v, 16, 64);   // quad0+1 -> unit 2w; quad2+3 -> unit 2w+1
            if ((quad & 1) == 0){
                size_t gu = (size_t)(ubase + 2*w + (quad >> 1));
                out[gu*ROWLEN + tc*16 + l16] = v;
            }
        }
    }
}

__global__ __launch_bounds__(256)
void ion_kernel(const float* __restrict__ Z,
                const float* __restrict__ Wion,
                const float* __restrict__ bion,
                float* __restrict__ out1)
{
    int gid = blockIdx.x*256 + threadIdx.x;   // 131072 threads, 4 elems each
    int e0 = gid*4;
    float4 v;
    float* pv = &v.x;
    #pragma unroll
    for (int qi = 0; qi < 4; ++qi){
        int e = e0 + qi;
        int j = e & 31, mm = (e >> 5) & 7;
        pv[qi] = fast_silu(Z[mm] * Wion[j] + bion[j]);
    }
    *(float4*)&out1[e0] = v;
}

extern "C" void kernel_launch(void* const* d_in, const int* in_sizes, int n_in,
                              void* d_out, int out_size, void* d_ws, size_t ws_size,
                              hipStream_t stream)
{
    const float* r    = (const float*)d_in[0];
    const float* Rion = (const float*)d_in[1];
    const float* Z    = (const float*)d_in[2];
    const float* W0   = (const float*)d_in[3];
    const float* b0   = (const float*)d_in[4];
    const float* W1   = (const float*)d_in[5];
    const float* b1   = (const float*)d_in[6];
    const float* Wion = (const float*)d_in[7];
    const float* bion = (const float*)d_in[8];
    float* out = (float*)d_out;

    el_kernel<<<dim3(512), dim3(512), 0, stream>>>(r, Rion, W0, b0, W1, b1, out);
    ion_kernel<<<dim3(512), dim3(256), 0, stream>>>(Z, Wion, bion, out + OUT_EL);
}

// Round 3
// 181.618 us; speedup vs baseline: 1.3033x; 1.0399x over previous
//
#include <hip/hip_runtime.h>

// InputPreprocessor — B=2048, N=32, M=8, D_PAIR=37, H=128.
// features_el_el in the reference is DEAD CODE. Live outputs (both f32):
//   out0 = features_el  [B,N,424]  (ion-summed 2-layer silu MLP || flat feats)
//   out1 = features_ion [B,8,32]
// R10 = R9 + latency/VALU trims (structure unchanged):
//  - r[] software pipeline: iter it prefetches it+1's 3 floats into rotating
//    registers -> removes the per-iteration global-load stall at the head of
//    the dependency chain (feat -> l0 -> l1 is strictly serial per wave).
//  - RBF constants (mu, 1/sigma) hoisted out of the it-loop: they depend only
//    on phase (f = phase+4k). LDS/global offsets become compile-time:
//    f&7 = phase+4*(k&1), f>>3 = k>>1.
//  - ion_kernel folded into el prologue (2 elems/thread, 512x512 grid) ->
//    one launch total.
//  - s_setprio(1) around layer-1's pure-MFMA cluster (waves are barrier-free
//    and phase-diverse -> T5-favorable).
// R9 carried: h0 layer0->layer1 via LDS round-trip (bf16 [16e][128ch]/wave,
// row-XOR swizzle ^(e&7)<<3, conflict-free b64 w / b128 r), UNI aliasing of
// feat buffers (wave-private in-order LDS pipe, no in-loop barriers),
// LDS 81920 B = exactly 2 blocks/CU, v_cvt_pk_bf16_f32 packing, bias via
// 1.0-feature, b1 hoisted. __launch_bounds__(512,4) pins VGPR<=128.

typedef __attribute__((ext_vector_type(8))) short short8;
typedef __attribute__((ext_vector_type(4))) float f32x4;

#define ITERS     8
#define UNITS_IT  16          // units per block-iteration (128 edges)
#define ROWLEN    424
#define OUT_EL    27787264    // 65536*424

__device__ __forceinline__ unsigned short f2bf(float f){   // prologue staging only
    unsigned int u = __builtin_bit_cast(unsigned int, f);
    u += 0x7fffu + ((u >> 16) & 1u);     // RNE
    return (unsigned short)(u >> 16);
}
__device__ __forceinline__ unsigned int cvtpk_bf16(float lo, float hi){
    unsigned int r;
    asm("v_cvt_pk_bf16_f32 %0, %1, %2" : "=v"(r) : "v"(lo), "v"(hi));
    return r;   // [15:0]=bf16(lo), [31:16]=bf16(hi), RNE
}
__device__ __forceinline__ unsigned short bf16s(float x){
    return (unsigned short)cvtpk_bf16(x, x);
}
__device__ __forceinline__ float fast_silu(float x){
    return x * __builtin_amdgcn_rcpf(1.0f + __expf(-x));
}

__global__ __launch_bounds__(512, 4)
void el_kernel(const float* __restrict__ r,
               const float* __restrict__ Rion,
               const float* __restrict__ W0,
               const float* __restrict__ b0,
               const float* __restrict__ W1,
               const float* __restrict__ b1,
               const float* __restrict__ Z,
               const float* __restrict__ Wion,
               const float* __restrict__ bion,
               float* __restrict__ out)
{
    // MFMA-read layouts are [tile][chunk][lane64][8 shorts]: b128 = base+lane*16.
    __shared__ __align__(16) unsigned short W0L[8][2][64][8];   // 16384 B
    __shared__ __align__(16) unsigned short W1L[8][4][64][8];   // 32768 B
    // Per-wave 4096B union:
    //   shorts [0,512)    : featL  [4][16][8]  (feat^T k=0..31)      — feature phase
    //   shorts [512,640)  : featbL [16][8]     (k=32..36, 37=1.0)    — feature phase
    //   shorts [0,2048)   : h0     [16 edges][128 ch], XOR-swizzled  — layer0->layer1
    __shared__ __align__(16) unsigned short UNI[8][2048];       // 32768 B
    // total 81920 B -> exactly 2 blocks (1024 thr) / CU (zero LDS slack!)

    const int t    = threadIdx.x;
    const int lane = t & 63;
    const int w    = t >> 6;       // wave 0..7, owns units 2w,2w+1 (16 edges)
    const int quad = lane >> 4;
    const int l16  = lane & 15;

    // ---- stage W0L: A-frag for layer 0 (M=channel, K=feature) ----
    for (int i = t; i < 8*2*64*8; i += 512){
        int j = i & 7, ln = (i >> 3) & 63, ch = (i >> 9) & 1, tc = i >> 10;
        int q = ln >> 4, n = tc*16 + (ln & 15);
        float v = 0.f;
        if (ch == 0)            v = W0[(q*8 + j)*128 + n];
        else if (q == 0){
            if      (j < 5)     v = W0[(32 + j)*128 + n];
            else if (j == 5)    v = b0[n];                 // bias via 1.0-feature
        }
        ((unsigned short*)W0L)[i] = f2bf(v);
    }
    // ---- stage W1L: B-frag for layer 1 (K=channel, N=out-channel) ----
    for (int i = t; i < 8*4*64*8; i += 512){
        int j = i & 7, ln = (i >> 3) & 63, c = (i >> 9) & 3, tc = i >> 11;
        int k = c*32 + (ln >> 4)*8 + j, n = tc*16 + (ln & 15);
        ((unsigned short*)W1L)[i] = f2bf(W1[k*128 + n]);
    }
    // ---- featbL constant slots (iteration 0): j=5 -> 1.0, j=6,7 -> 0.
    // Raw LDS garbage here on it=0 can be bf16 Inf/NaN -> 0.0*Inf = NaN in the
    // layer-0 MFMA. For it>=1 these slots hold finite h0 leftovers (x 0.0
    // weight row = exact 0); j=5 is rewritten each iteration.
    if (t < 128){
        UNI[t >> 4][512 + (t & 15)*8 + 5] = 0x3F80;
        UNI[t >> 4][512 + (t & 15)*8 + 6] = 0;
        UNI[t >> 4][512 + (t & 15)*8 + 7] = 0;
    }

    // ---- ion output folded in: 2 elements per thread (524288 total) ----
    {
        int e0 = (blockIdx.x*512 + t)*2;           // even -> j0 < 31, no wrap
        int j0 = e0 & 31, mm = (e0 >> 5) & 7;
        float z = Z[mm];
        float2 v;
        v.x = fast_silu(z * Wion[j0]     + bion[j0]);
        v.y = fast_silu(z * Wion[j0 + 1] + bion[j0 + 1]);
        *(float2*)&out[OUT_EL + e0] = v;
    }

    // feature-phase mapping: 4 threads per edge; wave-local (frow>>4 == w)
    const int frow  = t >> 2;      // edge 0..127 = ul*8 + m
    const int phase = t & 3;
    const int ul    = frow >> 3;   // block-local unit 0..15
    const int m     = frow & 7;
    const int e16   = frow & 15;   // wave-local edge
    const float Rx = Rion[m*3+0];
    const float Ry = Rion[m*3+1];
    const float Rz = Rion[m*3+2];

    unsigned short* const uw = &UNI[w][0];
    const int h0row = l16 * 128;            // short offset of this lane's h0 row
    const int swz   = (l16 & 7) << 3;       // row-XOR swizzle (short granularity)

    const f32x4 zeroc = {0.f,0.f,0.f,0.f};

    // hoist layer-1 bias (8 VGPRs)
    float bias1[8];
    #pragma unroll
    for (int tc = 0; tc < 8; ++tc) bias1[tc] = b1[tc*16 + l16];

    // hoist per-thread RBF constants: f = phase + 4k, k = 0..7 (all phases)
    float muA[8], isA[8];
    #pragma unroll
    for (int k = 0; k < 8; ++k){
        float q = (float)(phase + 4*k) * (1.0f/31.0f);
        muA[k] = q*q*5.0f;
        isA[k] = 7.0f * __builtin_amdgcn_rcpf(1.0f + 5.0f*q);
    }

    const int ubase0 = blockIdx.x * (UNITS_IT * ITERS);

    // r software pipeline: current xyz in registers, prefetched one iter ahead
    float cx, cy, cz;
    {
        int gu = ubase0 + ul;
        cx = r[gu*3+0]; cy = r[gu*3+1]; cz = r[gu*3+2];
    }

    __syncthreads();   // weights staged; loop body is wave-local (no in-loop barriers)

    for (int it = 0; it < ITERS; ++it){
        const int ubase = ubase0 + it * UNITS_IT;

        // prefetch next iteration's r (wave-uniform branch; consumed next iter)
        float nx = 0.f, ny = 0.f, nz = 0.f;
        if (it < ITERS-1){
            int gun = ubase + UNITS_IT + ul;
            nx = r[gun*3+0]; ny = r[gun*3+1]; nz = r[gun*3+2];
        }

        // ---------- features: bf16 -> featL/featbL + exact f32 -> out ----------
        {
            int gu = ubase + ul;
            float dx = cx - Rx;
            float dy = cy - Ry;
            float dz = cz - Rz;
            float d2 = dx*dx + dy*dy + dz*dz;
            float d  = __builtin_amdgcn_sqrtf(d2);
            float* orow = &out[(size_t)gu*ROWLEN + 128 + m*37];
            // RBF slots: f = phase+4k -> f>>3 = k>>1, f&7 = phase+4*(k&1)
            #pragma unroll
            for (int k = 0; k < 8; ++k){
                float uu  = (d - muA[k]) * isA[k];
                float val = d2 * __expf(-d - uu*uu);
                orow[phase + 4*k] = val;
                uw[(k >> 1)*128 + e16*8 + phase + ((k & 1) << 2)] = bf16s(val);
            }
            // tail features (f = 32..36) + per-iter rewrite of the 1.0 slot
            if (phase == 0){
                orow[32] = d;  uw[512 + e16*8 + 0] = bf16s(d);
                orow[36] = dz; uw[512 + e16*8 + 4] = bf16s(dz);
            } else if (phase == 1){
                float v = __builtin_amdgcn_rcpf(d + 0.01f);
                orow[33] = v;  uw[512 + e16*8 + 1] = bf16s(v);
            } else if (phase == 2){
                orow[34] = dx; uw[512 + e16*8 + 2] = bf16s(dx);
            } else {
                orow[35] = dy; uw[512 + e16*8 + 3] = bf16s(dy);
                uw[512 + e16*8 + 5] = 0x3F80;
            }
        }

        // ---------- layer 0 (transposed): D0 = W0^T @ feat^T ----------
        short8 bf0 = *(const short8*)&uw[quad*128 + l16*8];   // k = quad*8+j
        short8 bf1 = *(const short8*)&uw[512 + l16*8];        // k = 32+j
        // featL/featbL now dead in LDS -> h0 may overwrite the union.
        #pragma unroll
        for (int tc = 0; tc < 8; ++tc){
            short8 a0 = *(const short8*)&W0L[tc][0][lane][0];
            short8 a1 = *(const short8*)&W0L[tc][1][lane][0];
            f32x4 acc = __builtin_amdgcn_mfma_f32_16x16x32_bf16(a0, bf0, zeroc, 0, 0, 0);
            acc       = __builtin_amdgcn_mfma_f32_16x16x32_bf16(a1, bf1, acc,   0, 0, 0);
            // C-layout: lane holds ch n = tc*16 + quad*4 + rr, edge = l16.
            unsigned int p01 = cvtpk_bf16(fast_silu(acc[0]), fast_silu(acc[1]));
            unsigned int p23 = cvtpk_bf16(fast_silu(acc[2]), fast_silu(acc[3]));
            unsigned long long pk = (unsigned long long)p01 |
                                    ((unsigned long long)p23 << 32);
            // h0[edge=l16][ch], swizzled; b64 write, conflict-free
            *(unsigned long long*)&uw[h0row + ((tc*16 + quad*4) ^ swz)] = pk;
        }

        // ---------- layer 1: D1[e][n] = h0[e][k] W1[k][n] ----------
        // A-frag: lane needs h0[edge=l16][k=c*32+quad*8+j]; same row-XOR swizzle.
        short8 afk[4];
        #pragma unroll
        for (int c = 0; c < 4; ++c)
            afk[c] = *(const short8*)&uw[h0row + ((c*32 + quad*8) ^ swz)];

        f32x4 acc1[8];
        #pragma unroll
        for (int i = 0; i < 8; ++i) acc1[i] = zeroc;
        __builtin_amdgcn_s_setprio(1);       // pure-MFMA cluster; waves are phase-diverse
        #pragma unroll
        for (int c = 0; c < 4; ++c){
            #pragma unroll
            for (int tc = 0; tc < 8; ++tc){
                short8 bw = *(const short8*)&W1L[tc][c][lane][0];
                acc1[tc] = __builtin_amdgcn_mfma_f32_16x16x32_bf16(afk[c], bw, acc1[tc], 0, 0, 0);
            }
        }
        __builtin_amdgcn_s_setprio(0);
        // bias + silu + ion-sum over rows, store one_el f32
        #pragma unroll
        for (int tc = 0; tc < 8; ++tc){
            float v = 0.f;
            #pragma unroll
            for (int rr = 0; rr < 4; ++rr) v += fast_silu(acc1[tc][rr] + bias1[tc]);
            v += __shfl_xor(v, 16, 64);   // quad0+1 -> unit 2w; quad2+3 -> unit 2w+1
            if ((quad & 1) == 0){
                size_t gu = (size_t)(ubase + 2*w + (quad >> 1));
                out[gu*ROWLEN + tc*16 + l16] = v;
            }
        }

        cx = nx; cy = ny; cz = nz;   // rotate r pipeline
    }
}

extern "C" void kernel_launch(void* const* d_in, const int* in_sizes, int n_in,
                              void* d_out, int out_size, void* d_ws, size_t ws_size,
                              hipStream_t stream)
{
    const float* r    = (const float*)d_in[0];
    const float* Rion = (const float*)d_in[1];
    const float* Z    = (const float*)d_in[2];
    const float* W0   = (const float*)d_in[3];
    const float* b0   = (const float*)d_in[4];
    const float* W1   = (const float*)d_in[5];
    const float* b1   = (const float*)d_in[6];
    const float* Wion = (const float*)d_in[7];
    const float* bion = (const float*)d_in[8];
    float* out = (float*)d_out;

    el_kernel<<<dim3(512), dim3(512), 0, stream>>>(r, Rion, W0, b0, W1, b1,
                                                   Z, Wion, bion, out);
}